// Round 1
// baseline (363.441 us; speedup 1.0000x reference)
//
#include <hip/hip_runtime.h>
#include <math.h>

// Twist (axis-angle) -> rotation matrix, Rodrigues formula.
// Input:  [B*R, 3] float32, B*R = 8,388,608 (divisible by 256).
// Output: [B*R, 3, 3] float32 row-major.
//
// Memory-bound: 100.7 MB read + 302 MB write. All global traffic staged
// through LDS so every global access is lane-stride-1 coalesced dwords.

#define TPB 256

__global__ __launch_bounds__(TPB) void twist2mat_kernel(
    const float* __restrict__ in, float* __restrict__ out) {
    const int tid = threadIdx.x;
    const int base_in  = blockIdx.x * (3 * TPB);   // floats
    const int base_out = blockIdx.x * (9 * TPB);   // floats

    __shared__ float si[3 * TPB];   // 3 KB
    __shared__ float so[9 * TPB];   // 9 KB

    // Coalesced global->LDS load: 3 x (64 lanes * 4B contiguous) per wave.
    si[tid]            = in[base_in + tid];
    si[tid + TPB]      = in[base_in + tid + TPB];
    si[tid + 2 * TPB]  = in[base_in + tid + 2 * TPB];
    __syncthreads();

    // LDS read at stride 3 (coprime with 32 banks -> 2-way, free).
    const float w0 = si[3 * tid + 0];
    const float w1 = si[3 * tid + 1];
    const float w2 = si[3 * tid + 2];

    const float n2  = fmaf(w0, w0, fmaf(w1, w1, w2 * w2));
    const float t   = fmaxf(sqrtf(n2), 1e-5f);   // rot_angle = clamp(||w||, 1e-5)
    const float inv = 1.0f / t;
    const float a0 = w0 * inv, a1 = w1 * inv, a2 = w2 * inv;

    float s, c;
    __sincosf(t, &s, &c);
    const float c1 = 1.0f - c;

    // AA = a a^T - (a.a) I  (exact A@A even when axis is not unit length,
    // matching the reference's explicit matmul in the clamped branch).
    const float aa = fmaf(a0, a0, fmaf(a1, a1, a2 * a2));

    // R = I + s*A + c1*AA, row-major. Write at stride 9 (coprime, free).
    float* r = &so[9 * tid];
    r[0] = fmaf(c1, fmaf(a0, a0, -aa), 1.0f);
    r[1] = fmaf(c1, a0 * a1, -s * a2);
    r[2] = fmaf(c1, a0 * a2,  s * a1);
    r[3] = fmaf(c1, a0 * a1,  s * a2);
    r[4] = fmaf(c1, fmaf(a1, a1, -aa), 1.0f);
    r[5] = fmaf(c1, a1 * a2, -s * a0);
    r[6] = fmaf(c1, a0 * a2, -s * a1);
    r[7] = fmaf(c1, a1 * a2,  s * a0);
    r[8] = fmaf(c1, fmaf(a2, a2, -aa), 1.0f);
    __syncthreads();

    // Coalesced LDS->global store: 9 x (64 lanes * 4B contiguous) per wave.
#pragma unroll
    for (int k = 0; k < 9; ++k)
        out[base_out + tid + TPB * k] = so[tid + TPB * k];
}

extern "C" void kernel_launch(void* const* d_in, const int* in_sizes, int n_in,
                              void* d_out, int out_size, void* d_ws, size_t ws_size,
                              hipStream_t stream) {
    (void)n_in; (void)out_size; (void)d_ws; (void)ws_size;
    const float* in = (const float*)d_in[0];
    float* out = (float*)d_out;
    const int nrot = in_sizes[0] / 3;          // 8,388,608
    const int grid = nrot / TPB;               // exact: 32,768 blocks
    twist2mat_kernel<<<grid, TPB, 0, stream>>>(in, out);
}

// Round 3
// 353.573 us; speedup vs baseline: 1.0279x; 1.0279x over previous
//
#include <hip/hip_runtime.h>
#include <math.h>

// Twist (axis-angle) -> rotation matrix, Rodrigues formula.
// Input:  [8388608, 3] f32 ; Output: [8388608, 3, 3] f32.
// Memory-bound streaming: 100.7 MB read + 302 MB write, floor ~64 us.
//
// v2b: 4 rotations/thread so output = exactly 9 x 16B/thread. All global
// traffic is lane-stride-16B dwordx4 (nontemporal), staged through LDS.
// Uses clang ext_vector_type (not HIP float4 class) so the nontemporal
// builtins accept the pointers.

typedef float v4f __attribute__((ext_vector_type(4)));

#define TPB 256
#define RPT 4                    // rotations per thread
#define RPB (TPB * RPT)          // 1024 rotations per block
#define IN_F4 (RPB * 3 / 4)      // 768  v4f in  per block
#define OUT_F4 (RPB * 9 / 4)     // 2304 v4f out per block (36 KB)

__global__ __launch_bounds__(TPB) void twist2mat_kernel(
    const v4f* __restrict__ in4, v4f* __restrict__ out4) {
    const int tid = threadIdx.x;
    const int bin  = blockIdx.x * IN_F4;
    const int bout = blockIdx.x * OUT_F4;

    __shared__ v4f buf[OUT_F4];   // 36 KB -> 4 blocks/CU (16 waves)

    // Phase 1: coalesced global->LDS (3 x dwordx4 per thread, stride-256 v4).
#pragma unroll
    for (int k = 0; k < 3; ++k)
        buf[tid + TPB * k] = __builtin_nontemporal_load(&in4[bin + tid + TPB * k]);
    __syncthreads();

    // Phase 2: this thread's 4 rotations (12 floats) -> registers.
    const v4f x0 = buf[3 * tid + 0];
    const v4f x1 = buf[3 * tid + 1];
    const v4f x2 = buf[3 * tid + 2];
    __syncthreads();   // all reads done before buf is reused for output

    const float w[12] = {x0.x, x0.y, x0.z, x0.w,
                         x1.x, x1.y, x1.z, x1.w,
                         x2.x, x2.y, x2.z, x2.w};
    float o[36];
#pragma unroll
    for (int j = 0; j < 4; ++j) {
        const float w0 = w[3 * j], w1 = w[3 * j + 1], w2 = w[3 * j + 2];
        const float n2  = fmaf(w0, w0, fmaf(w1, w1, w2 * w2));
        const float t   = fmaxf(sqrtf(n2), 1e-5f);   // clamp(||w||, 1e-5)
        const float inv = 1.0f / t;
        const float a0 = w0 * inv, a1 = w1 * inv, a2 = w2 * inv;
        float s, c;
        __sincosf(t, &s, &c);
        const float c1 = 1.0f - c;
        // AA = a a^T - (a.a) I  (exact A@A for the clamped non-unit case).
        const float aa = fmaf(a0, a0, fmaf(a1, a1, a2 * a2));
        float* r = &o[9 * j];
        r[0] = fmaf(c1, fmaf(a0, a0, -aa), 1.0f);
        r[1] = fmaf(c1, a0 * a1, -s * a2);
        r[2] = fmaf(c1, a0 * a2,  s * a1);
        r[3] = fmaf(c1, a0 * a1,  s * a2);
        r[4] = fmaf(c1, fmaf(a1, a1, -aa), 1.0f);
        r[5] = fmaf(c1, a1 * a2, -s * a0);
        r[6] = fmaf(c1, a0 * a2, -s * a1);
        r[7] = fmaf(c1, a1 * a2,  s * a0);
        r[8] = fmaf(c1, fmaf(a2, a2, -aa), 1.0f);
    }

    // Phase 3: registers -> LDS in output-linear order (9 x ds_write_b128).
#pragma unroll
    for (int k = 0; k < 9; ++k) {
        v4f v = {o[4 * k + 0], o[4 * k + 1], o[4 * k + 2], o[4 * k + 3]};
        buf[9 * tid + k] = v;
    }
    __syncthreads();

    // Phase 4: coalesced LDS->global, nontemporal dwordx4 (pure streaming).
#pragma unroll
    for (int k = 0; k < 9; ++k)
        __builtin_nontemporal_store(buf[tid + TPB * k],
                                    &out4[bout + tid + TPB * k]);
}

extern "C" void kernel_launch(void* const* d_in, const int* in_sizes, int n_in,
                              void* d_out, int out_size, void* d_ws, size_t ws_size,
                              hipStream_t stream) {
    (void)n_in; (void)out_size; (void)d_ws; (void)ws_size;
    const v4f* in4 = (const v4f*)d_in[0];
    v4f* out4 = (v4f*)d_out;
    const int nrot = in_sizes[0] / 3;       // 8,388,608
    const int grid = nrot / RPB;            // exact: 8192 blocks
    twist2mat_kernel<<<grid, TPB, 0, stream>>>(in4, out4);
}